// Round 20
// baseline (34.405 us; speedup 1.0000x reference)
//
#include <hip/hip_runtime.h>

typedef __bf16 bf16;
typedef __attribute__((ext_vector_type(4)))  __bf16 bf16x4;
typedef __attribute__((ext_vector_type(8)))  __bf16 bf16x8;
typedef __attribute__((ext_vector_type(4)))  float  f32x4;
typedef __attribute__((ext_vector_type(16))) float  f32x16;

constexpr int B_ = 16, N_ = 256, K_ = 10, C_ = 100, CP_ = 112;
constexpr float NL2E = -0.7213475204444817f;             // -0.5*log2(e)
constexpr int BF_SLICE = 16 * 2 * 128 * 8;               // 32768 bf16 per (b,k)

__device__ inline bf16x8 cvt8(const float* p) {
    float4 a = *(const float4*)p, b = *(const float4*)(p + 4);
    bf16x8 r = {(bf16)a.x, (bf16)a.y, (bf16)a.z, (bf16)a.w,
                (bf16)b.x, (bf16)b.y, (bf16)b.z, (bf16)b.w};
    return r;
}
__device__ inline bf16x8 cvt4z(const float* p) {          // 4 valid + 4 zeros
    float4 a = *(const float4*)p;
    bf16x8 r = {(bf16)a.x, (bf16)a.y, (bf16)a.z, (bf16)a.w,
                (bf16)0.0f, (bf16)0.0f, (bf16)0.0f, (bf16)0.0f};
    return r;
}

// ---------------------------------------------------------------------------
// K1 (R18 verbatim): xkT fragment-ready via MFMA 32x32x16, wave = c-tile.
//   Coalesced x staging (unroll 4); scattered fragment-ready stores (R19's
//   LDS-staged store variant regressed - stores are latency-tolerant).
// Grid 1280 XCD-swizzled blocks x 256 thr; LDS 12.9KB.
// ---------------------------------------------------------------------------
__global__ __launch_bounds__(256, 4) void xk_gemm(
    const float* __restrict__ x, const float* __restrict__ W,
    const float* __restrict__ bias, bf16* __restrict__ xkT)
{
    __shared__ float xs[32 * 101 + 16];            // [m32][100+pad]

    const int bid = blockIdx.x;
    const int xcd = bid & 7, s = bid >> 3;         // s: 0..159
    const int b  = xcd + 8 * (s / 80);
    const int rr = s % 80, kk = rr >> 3, mq = rr & 7;
    const int tid = threadIdx.x;
    const int w = tid >> 6, l = tid & 63, l31 = l & 31, h = l >> 5;
    const int c = w * 32 + l31;                    // A row this lane loads

    // ---- coalesced x staging: 32 rows x 100 floats (row stride 1000) ----
    const float* xb = x + ((size_t)(b * N_ + mq * 32) * K_ + kk) * C_;
    #pragma unroll 4
    for (int idx = tid; idx < 800; idx += 256) {   // 800 float4s
        int row = idx / 25, q = idx - row * 25;
        float4 v = *(const float4*)(xb + (size_t)row * (K_ * C_) + q * 4);
        *(float4*)(&xs[row * 101 + q * 4]) = v;
    }

    const bf16x8 zf = {(bf16)0.f,(bf16)0.f,(bf16)0.f,(bf16)0.f,
                       (bf16)0.f,(bf16)0.f,(bf16)0.f,(bf16)0.f};

    // A-frags from global W (40KB, L2-hot)
    bf16x8 af[7];
    const float* Wrow = W + (size_t)c * C_;
    #pragma unroll
    for (int js = 0; js < 7; ++js) {
        const int jb = js * 16 + h * 8;
        af[js] = zf;
        if (c < C_) {
            if (jb + 8 <= C_)      af[js] = cvt8(Wrow + jb);
            else if (jb < C_)      af[js] = cvt4z(Wrow + jb);   // jb == 96
        }
    }

    f32x16 acc;
    #pragma unroll
    for (int r = 0; r < 16; ++r) {
        int crow = w * 32 + (r & 3) + 8 * (r >> 2) + 4 * h;
        acc[r] = (crow < C_) ? bias[crow] : 0.0f;
    }

    __syncthreads();

    // ---- B-frags from LDS + MFMA ----
    #pragma unroll
    for (int js = 0; js < 7; ++js) {
        const int jb = js * 16 + h * 8;            // up to 104; padded array
        bf16x8 b0 = zf;
        if (jb < C_) b0 = cvt8(&xs[l31 * 101 + jb]);  // pad garbage x af==0
        acc = __builtin_amdgcn_mfma_f32_32x32x16_bf16(af[js], b0, acc, 0, 0, 0);
    }

    // ---- store in fragment-ready layout: Bf[ks][h][c][i], i=m&7 ----
    bf16* op = xkT + (size_t)(b * K_ + kk) * BF_SLICE;
    const int mg = mq * 32 + l31;
    const int base = (((mg >> 4) << 1) + ((mg >> 3) & 1)) * 1024 + (mg & 7);
    #pragma unroll
    for (int r = 0; r < 16; ++r) {
        const int crow = w * 32 + (r & 3) + 8 * (r >> 2) + 4 * h;
        op[base + crow * 8] = (bf16)acc[r];
    }
}

// ---------------------------------------------------------------------------
// K2 (k-PAIR): block = (b, kp, n32) computes k0=kp AND k1=kp+5.
//   Pseudo/adj read ONCE for both k (halves K2's dominant L2 traffic term);
//   phase 1 = R18's coalesced loads + dual quadratic/exp2 -> two 16KB
//   swizzled ag tiles; phase 2 = dual MFMA chains, B line-contiguous from
//   fragment-ready xkT (two slices). One barrier.
// Grid 640 XCD-swizzled blocks x 256 thr; LDS 32KB; (256,2) for dual-acc VGPR.
// ---------------------------------------------------------------------------
__global__ __launch_bounds__(256, 2) void gauss_agg(
    const float* __restrict__ adj, const float* __restrict__ pseudo,
    const float* __restrict__ mu, const float* __restrict__ sigma,
    const bf16* __restrict__ xkT, float* __restrict__ out)
{
    __shared__ __align__(16) char lds0[32 * 512];  // ag tile k0
    __shared__ __align__(16) char lds1[32 * 512];  // ag tile k1

    const int bid = blockIdx.x;
    const int xcd = bid & 7, s = bid >> 3;         // s: 0..79
    const int b  = xcd + 8 * (s / 40);
    const int rr = s % 40, kp = rr >> 3, nh = rr & 7;
    const int k0 = kp, k1 = kp + 5;
    const int n32 = nh * 32;
    const int tid = threadIdx.x;
    const int w = tid >> 6, l = tid & 63, l31 = l & 31, h = l >> 5;

    // coefs for both kernels (uniform -> scalar loads)
    float A0[4], B0[4], g0c = 0.0f, A1[4], B1[4], g1c = 0.0f;
    #pragma unroll
    for (int d = 0; d < 4; ++d) {
        float sg0 = sigma[k0 * 4 + d], mv0 = mu[k0 * 4 + d];
        float al0 = NL2E / (1e-6f + sg0 * sg0);
        A0[d] = al0; B0[d] = -2.0f * al0 * mv0; g0c += al0 * mv0 * mv0;
        float sg1 = sigma[k1 * 4 + d], mv1 = mu[k1 * 4 + d];
        float al1 = NL2E / (1e-6f + sg1 * sg1);
        A1[d] = al1; B1[d] = -2.0f * al1 * mv1; g1c += al1 * mv1 * mv1;
    }

    // ---- phase 1: BOTH ag tiles, pseudo/adj read once (coalesced) ----
    const float* pbase = pseudo + (size_t)(b * N_ + n32) * N_ * 4;
    const float* abase = adj    + (size_t)(b * N_ + n32) * N_;
    #pragma unroll
    for (int i = 0; i < 8; ++i) {
        const int row = i * 4 + w;                 // wave owns one row/iter
        const float4* pr = (const float4*)(pbase + (size_t)row * N_ * 4);
        const float*  ar = abase + (size_t)row * N_;
        float4 p0 = pr[l];                         // 1KB contiguous per instr
        float4 p1 = pr[l + 64];
        float4 p2 = pr[l + 128];
        float4 p3 = pr[l + 192];
        float a0 = ar[l], a1 = ar[l + 64], a2 = ar[l + 128], a3 = ar[l + 192];

        float q0x = p0.x*p0.x, q0y = p0.y*p0.y, q0z = p0.z*p0.z, q0w = p0.w*p0.w;
        float q1x = p1.x*p1.x, q1y = p1.y*p1.y, q1z = p1.z*p1.z, q1w = p1.w*p1.w;
        float q2x = p2.x*p2.x, q2y = p2.y*p2.y, q2z = p2.z*p2.z, q2w = p2.w*p2.w;
        float q3x = p3.x*p3.x, q3y = p3.y*p3.y, q3z = p3.z*p3.z, q3w = p3.w*p3.w;

        float s00 = g0c + A0[0]*q0x + B0[0]*p0.x + A0[1]*q0y + B0[1]*p0.y
                        + A0[2]*q0z + B0[2]*p0.z + A0[3]*q0w + B0[3]*p0.w;
        float s01 = g0c + A0[0]*q1x + B0[0]*p1.x + A0[1]*q1y + B0[1]*p1.y
                        + A0[2]*q1z + B0[2]*p1.z + A0[3]*q1w + B0[3]*p1.w;
        float s02 = g0c + A0[0]*q2x + B0[0]*p2.x + A0[1]*q2y + B0[1]*p2.y
                        + A0[2]*q2z + B0[2]*p2.z + A0[3]*q2w + B0[3]*p2.w;
        float s03 = g0c + A0[0]*q3x + B0[0]*p3.x + A0[1]*q3y + B0[1]*p3.y
                        + A0[2]*q3z + B0[2]*p3.z + A0[3]*q3w + B0[3]*p3.w;

        float s10 = g1c + A1[0]*q0x + B1[0]*p0.x + A1[1]*q0y + B1[1]*p0.y
                        + A1[2]*q0z + B1[2]*p0.z + A1[3]*q0w + B1[3]*p0.w;
        float s11 = g1c + A1[0]*q1x + B1[0]*p1.x + A1[1]*q1y + B1[1]*p1.y
                        + A1[2]*q1z + B1[2]*p1.z + A1[3]*q1w + B1[3]*p1.w;
        float s12 = g1c + A1[0]*q2x + B1[0]*p2.x + A1[1]*q2y + B1[1]*p2.y
                        + A1[2]*q2z + B1[2]*p2.z + A1[3]*q2w + B1[3]*p2.w;
        float s13 = g1c + A1[0]*q3x + B1[0]*p3.x + A1[1]*q3y + B1[1]*p3.y
                        + A1[2]*q3z + B1[2]*p3.z + A1[3]*q3w + B1[3]*p3.w;

        #pragma unroll
        for (int t = 0; t < 4; ++t) {
            const int m  = l + 64 * t;
            const int ch = m >> 3, half = (m >> 2) & 1, pos = m & 3;
            const int off = row * 512 + ((ch ^ (row & 7)) * 16) + half * 8 + pos * 2;
            const float av = (t == 0) ? a0 : (t == 1) ? a1 : (t == 2) ? a2 : a3;
            const float sA = (t == 0) ? s00 : (t == 1) ? s01 : (t == 2) ? s02 : s03;
            const float sB = (t == 0) ? s10 : (t == 1) ? s11 : (t == 2) ? s12 : s13;
            *(bf16*)(lds0 + off) = (bf16)(__builtin_amdgcn_exp2f(sA) * av);
            *(bf16*)(lds1 + off) = (bf16)(__builtin_amdgcn_exp2f(sB) * av);
        }
    }
    __syncthreads();

    // ---- phase 2: dual-k MFMA, B-frags line-contiguous ----
    const bf16* bsl0 = xkT + (size_t)(b * K_ + k0) * BF_SLICE + (size_t)(w * 32 + l31) * 8;
    const bf16* bsl1 = xkT + (size_t)(b * K_ + k1) * BF_SLICE + (size_t)(w * 32 + l31) * 8;
    f32x16 acc0, acc1;
    #pragma unroll
    for (int i = 0; i < 16; ++i) { acc0[i] = 0.0f; acc1[i] = 0.0f; }

    #pragma unroll
    for (int ks = 0; ks < 16; ++ks) {
        const int aoff = l31 * 512 + (((ks * 2 + h) ^ (l31 & 7)) * 16);
        bf16x8 af0 = *(const bf16x8*)(lds0 + aoff);
        bf16x8 af1 = *(const bf16x8*)(lds1 + aoff);
        bf16x8 bf0 = *(const bf16x8*)(bsl0 + (size_t)(ks * 2 + h) * 1024);
        bf16x8 bf1 = *(const bf16x8*)(bsl1 + (size_t)(ks * 2 + h) * 1024);
        acc0 = __builtin_amdgcn_mfma_f32_32x32x16_bf16(af0, bf0, acc0, 0, 0, 0);
        acc1 = __builtin_amdgcn_mfma_f32_32x32x16_bf16(af1, bf1, acc1, 0, 0, 0);
    }

    const int c = w * 32 + l31;
    if (c < C_) {
        float* ob0 = out + (size_t)(b * K_ + k0) * C_ * N_ + (size_t)c * N_ + n32;
        float* ob1 = out + (size_t)(b * K_ + k1) * C_ * N_ + (size_t)c * N_ + n32;
        #pragma unroll
        for (int q = 0; q < 4; ++q) {
            float4 v0 = {acc0[4*q+0], acc0[4*q+1], acc0[4*q+2], acc0[4*q+3]};
            float4 v1 = {acc1[4*q+0], acc1[4*q+1], acc1[4*q+2], acc1[4*q+3]};
            *(float4*)(ob0 + 8 * q + 4 * h) = v0;
            *(float4*)(ob1 + 8 * q + 4 * h) = v1;
        }
    }
}

extern "C" void kernel_launch(void* const* d_in, const int* in_sizes, int n_in,
                              void* d_out, int out_size, void* d_ws, size_t ws_size,
                              hipStream_t stream)
{
    const float* x      = (const float*)d_in[0];
    const float* adj    = (const float*)d_in[1];
    const float* pseudo = (const float*)d_in[2];
    const float* mu     = (const float*)d_in[3];
    const float* sigma  = (const float*)d_in[4];
    const float* W      = (const float*)d_in[5];
    const float* bias   = (const float*)d_in[6];
    float* out = (float*)d_out;
    bf16* xkT  = (bf16*)d_ws;                      // 10.5 MB fragment-ready

    hipLaunchKernelGGL(xk_gemm, dim3(1280), dim3(256), 0, stream, x, W, bias, xkT);
    hipLaunchKernelGGL(gauss_agg, dim3(640), dim3(256), 0, stream,
                       adj, pseudo, mu, sigma, xkT, out);
}